// Round 8
// baseline (644.690 us; speedup 1.0000x reference)
//
#include <hip/hip_runtime.h>
#include <math.h>

// ---------------------------------------------------------------------------
// SGCN forward — R7: XCD-pinned fill (real XCC_ID, not blockIdx guess) +
// 16B-lane gather + gemm occupancy bump.
//
// R6 post-mortem: fill WRITE_SIZE stayed 121MB -> blockIdx&7 is NOT the XCD
// mapping; cross-XCD writes to the same col lines ping-pong through HBM.
// R7 fill: each 64-thread block reads its physical XCD id via
// s_getreg(HW_REG_XCC_ID) [learn_hip m09] and serves ONLY that XCD's 1/8
// dst-partition, grabbing edge chunks from a per-XCD ticket counter. col/cur
// lines for a partition then live in exactly one XCD's L2 -> write amp ~1.
// ---------------------------------------------------------------------------

typedef __attribute__((ext_vector_type(8))) __bf16 bf16x8;
typedef __attribute__((ext_vector_type(4))) float f32x4;
typedef __attribute__((ext_vector_type(2))) unsigned uv2;
typedef __attribute__((ext_vector_type(4))) unsigned uv4;
typedef __attribute__((ext_vector_type(2))) float fv2;

__device__ inline unsigned bfpack(float lo, float hi) {
    unsigned a = __float_as_uint(lo), b = __float_as_uint(hi);
    a += 0x7fffu + ((a >> 16) & 1u);          // RNE to bf16
    b += 0x7fffu + ((b >> 16) & 1u);
    return (a >> 16) | (b & 0xffff0000u);
}
__device__ inline float bflo(unsigned p) { return __uint_as_float(p << 16); }
__device__ inline float bfhi(unsigned p) { return __uint_as_float(p & 0xffff0000u); }

__device__ inline float tanh_fast(float x) {
    float e = __builtin_amdgcn_exp2f(x * 2.8853900817779268f);
    return 1.0f - 2.0f * __builtin_amdgcn_rcpf(e + 1.0f);
}

__device__ inline bf16x8 as_frag(uv4 u) { return __builtin_bit_cast(bf16x8, u); }

__device__ inline int xcc_id() {
    unsigned v;
    asm volatile("s_getreg_b32 %0, hwreg(HW_REG_XCC_ID)" : "=s"(v));
    return (int)(v & 7u);
}

// ------------------------------- CSR build ---------------------------------

// blocks [0, cvtBlocks): fp32 -> bf16-pair convert of x.
// blocks [cvtBlocks, ...): degree histogram with nt edge-stream reads.
__global__ void __launch_bounds__(256) pre_k(
    const fv2* __restrict__ xf, unsigned* __restrict__ xb, int m,
    const int* __restrict__ pos, const int* __restrict__ neg,
    int* __restrict__ deg, int E, int n, int cvtBlocks)
{
    if ((int)blockIdx.x < cvtBlocks) {
        int i = blockIdx.x * 256 + threadIdx.x;
        if (i < m) {
            fv2 v = __builtin_nontemporal_load(&xf[i]);
            xb[i] = bfpack(v.x, v.y);
        }
    } else {
        int e = (blockIdx.x - cvtBlocks) * 256 + threadIdx.x;
        if (e < E)
            atomicAdd(&deg[__builtin_nontemporal_load(&pos[E + e])], 1);
        else if (e < 2 * E)
            atomicAdd(&deg[n + __builtin_nontemporal_load(&neg[E + (e - E)])], 1);
    }
}

__global__ void __launch_bounds__(256) scan1_k(
    const int* __restrict__ deg, int* __restrict__ cur,
    int* __restrict__ bsum, int n2)
{
    __shared__ int s[256];
    int tid = threadIdx.x;
    int i = blockIdx.x * 256 + tid;
    int v = (i < n2) ? deg[i] : 0;
    s[tid] = v;
    __syncthreads();
    for (int off = 1; off < 256; off <<= 1) {
        int t = (tid >= off) ? s[tid - off] : 0;
        __syncthreads();
        s[tid] += t;
        __syncthreads();
    }
    if (i < n2) cur[i] = s[tid] - v;
    if (tid == 255) bsum[blockIdx.x] = s[255];
}

__global__ void __launch_bounds__(1024) scan2_k(int* __restrict__ bsum, int nb)
{
    __shared__ int s[1024];
    int tid = threadIdx.x;
    int v = (tid < nb) ? bsum[tid] : 0;
    s[tid] = v;
    __syncthreads();
    for (int off = 1; off < 1024; off <<= 1) {
        int t = (tid >= off) ? s[tid - off] : 0;
        __syncthreads();
        s[tid] += t;
        __syncthreads();
    }
    if (tid < nb) bsum[tid] = s[tid] - v;
}

__global__ void __launch_bounds__(256) scan3_k(
    int* __restrict__ cur, const int* __restrict__ bsum, int n2)
{
    int i = blockIdx.x * 256 + threadIdx.x;
    if (i < n2) cur[i] += bsum[blockIdx.x];
}

// XCD-pinned fill. One wave per block; block serves partition = its real
// XCD id; per-XCD ticket counter hands out edge chunks.
__global__ void __launch_bounds__(64) fill_k(
    const int* __restrict__ pos, const int* __restrict__ neg,
    int* __restrict__ cur, int* __restrict__ col, int* __restrict__ ticket,
    int E, int n)
{
    int xcc = xcc_id();
    int n2 = 2 * n;
    int lo = (int)(((long long)n2 * xcc) >> 3);
    int hi = (int)(((long long)n2 * (xcc + 1)) >> 3);
    int lane = threadIdx.x;
    const int CHUNK = 8192;
    for (;;) {
        int base = 0;
        if (lane == 0) base = atomicAdd(&ticket[xcc], CHUNK);
        base = __shfl(base, 0);
        if (base >= 2 * E) break;
        int end = min(base + CHUNK, 2 * E);
        for (int e = base + lane; e < end; e += 64) {
            int node;
            if (e < E) node = __builtin_nontemporal_load(&pos[E + e]);
            else       node = n + __builtin_nontemporal_load(&neg[e - E + E]);
            if (node >= lo && node < hi) {
                int src = (e < E) ? __builtin_nontemporal_load(&pos[e])
                                  : __builtin_nontemporal_load(&neg[e - E]);
                int slot = atomicAdd(&cur[node], 1);
                col[slot] = src;
            }
        }
    }
}

// ----------------------------- pull gather ---------------------------------
// One wave per node (grid-stride). lane = 8g+f: 8 lanes cover a 128B bf16
// row (16B = uv4 per lane). Groups 0..3 pull pos edges (stride 4), groups
// 4..7 pull neg edges. 2-round xor reduction within each half.
__global__ void __launch_bounds__(256, 8) gather_k(
    const unsigned* __restrict__ tab,   // n x 32 uints (bf16 pairs)
    const int* __restrict__ cur, const int* __restrict__ col,
    unsigned* __restrict__ Aout,        // n x 64 uints
    int n)
{
    int tid = threadIdx.x;
    int wave = tid >> 6, lane = tid & 63, g = lane >> 3, f = lane & 7;
    int gq = g & 3;
    bool isNeg = g >= 4;
    int stride = gridDim.x * 4;
    for (int node = blockIdx.x * 4 + wave; node < n; node += stride) {
        int p0 = node ? cur[node - 1] : 0;
        int p1 = cur[node];
        int q0 = cur[n + node - 1];     // node==0 -> cur[n-1] == E
        int q1 = cur[n + node];
        int it0 = isNeg ? q0 : p0;
        int it1 = isNeg ? q1 : p1;
        float a0 = 0.f, a1 = 0.f, a2 = 0.f, a3 = 0.f;
        float a4 = 0.f, a5 = 0.f, a6 = 0.f, a7 = 0.f;
        #pragma unroll 2
        for (int it = it0 + gq; it < it1; it += 4) {
            int s = __builtin_nontemporal_load(&col[it]);
            uv4 t = *(const uv4*)(tab + (size_t)s * 32 + 4 * f);
            a0 += bflo(t.x); a1 += bfhi(t.x);
            a2 += bflo(t.y); a3 += bfhi(t.y);
            a4 += bflo(t.z); a5 += bfhi(t.z);
            a6 += bflo(t.w); a7 += bfhi(t.w);
        }
        // reduce the 4 groups within each 32-lane half
        a0 += __shfl_xor(a0, 8);  a1 += __shfl_xor(a1, 8);
        a2 += __shfl_xor(a2, 8);  a3 += __shfl_xor(a3, 8);
        a4 += __shfl_xor(a4, 8);  a5 += __shfl_xor(a5, 8);
        a6 += __shfl_xor(a6, 8);  a7 += __shfl_xor(a7, 8);
        a0 += __shfl_xor(a0, 16); a1 += __shfl_xor(a1, 16);
        a2 += __shfl_xor(a2, 16); a3 += __shfl_xor(a3, 16);
        a4 += __shfl_xor(a4, 16); a5 += __shfl_xor(a5, 16);
        a6 += __shfl_xor(a6, 16); a7 += __shfl_xor(a7, 16);
        float r = 1.0f / (float)max(it1 - it0, 1);
        if (g == 0 || g == 4) {
            uv4 o;
            o.x = bfpack(a0 * r, a1 * r);
            o.y = bfpack(a2 * r, a3 * r);
            o.z = bfpack(a4 * r, a5 * r);
            o.w = bfpack(a6 * r, a7 * r);
            unsigned* dst = Aout + (size_t)node * 64 + (isNeg ? 32 : 0) + 4 * f;
            __builtin_nontemporal_store(o, (uv4*)dst);
        }
    }
}

// ------------------------------ MFMA dense ---------------------------------
template<int LAYER>
__global__ void __launch_bounds__(256, 3) gemm_k(
    const unsigned* __restrict__ A,      // n x 64 uints  [agg_p|agg_n]
    const unsigned* __restrict__ T,      // n x 32 uints  (x or z bf16)
    const float* __restrict__ Wp, const float* __restrict__ bp,
    const float* __restrict__ Wn, const float* __restrict__ bn,
    void* __restrict__ outv, int n)
{
    __shared__ unsigned short Bl[64 * 200];   // 25.6 KB
    __shared__ float Cs[4][16 * 68];          // 17.4 KB, per-wave C transpose
    int tid = threadIdx.x;
    for (int idx = tid; idx < 64 * 192; idx += 256) {
        int k = idx >> 6, nn = idx & 63;
        float v = 0.f;
        if (LAYER == 1) {
            if (nn < 32) { if (k < 64) v = Wp[k * 32 + nn];
                           else if (k >= 128) v = Wp[(k - 64) * 32 + nn]; }
            else         { if (k >= 64) v = Wn[(k - 64) * 32 + (nn - 32)]; }
        } else {
            if (nn < 32) { if (k < 32) v = Wp[k * 32 + nn];
                           else if (k >= 96 && k < 160) v = Wp[(k - 64) * 32 + nn]; }
            else         { if (k >= 32 && k < 96) v = Wn[(k - 32) * 32 + (nn - 32)];
                           else if (k >= 160) v = Wn[(k - 96) * 32 + (nn - 32)]; }
        }
        unsigned u = __float_as_uint(v);
        u += 0x7fffu + ((u >> 16) & 1u);
        Bl[nn * 200 + k] = (unsigned short)(u >> 16);
    }
    __syncthreads();

    int wave = tid >> 6, lane = tid & 63;
    int lm = lane & 15, lg = lane >> 4;

    bf16x8 Bf[4][6];
    #pragma unroll
    for (int t = 0; t < 4; ++t)
        #pragma unroll
        for (int s = 0; s < 6; ++s)
            Bf[t][s] = *(const bf16x8*)&Bl[(t * 16 + lm) * 200 + s * 32 + lg * 8];

    float bias[4];
    #pragma unroll
    for (int t = 0; t < 4; ++t) {
        int nc = t * 16 + lm;
        bias[t] = (nc < 32) ? bp[nc] : bn[nc - 32];
    }

    float* Cw = Cs[wave];
    int ntiles = (n + 15) >> 4;
    for (int tile = blockIdx.x * 4 + wave; tile < ntiles; tile += gridDim.x * 4) {
        int node0 = tile * 16;
        int ra = min(node0 + lm, n - 1);          // A-frag: m = lane&15
        const uv4* Arow = (const uv4*)(A + (size_t)ra * 64);
        const uv4* Trow = (const uv4*)(T + (size_t)ra * 32);
        bf16x8 Af[6];
        #pragma unroll
        for (int s = 0; s < 4; ++s)
            Af[s] = as_frag(__builtin_nontemporal_load(&Arow[s * 4 + lg]));
        #pragma unroll
        for (int s = 0; s < 2; ++s) Af[4 + s] = as_frag(Trow[s * 4 + lg]);

        #pragma unroll
        for (int t = 0; t < 4; ++t) {
            f32x4 c = {0.f, 0.f, 0.f, 0.f};
            #pragma unroll
            for (int s = 0; s < 6; ++s)
                c = __builtin_amdgcn_mfma_f32_16x16x32_bf16(Af[s], Bf[t][s], c, 0, 0, 0);
            #pragma unroll
            for (int r = 0; r < 4; ++r)
                Cw[(lg * 4 + r) * 68 + t * 16 + lm] = tanh_fast(c[r] + bias[t]);
        }
        __builtin_amdgcn_wave_barrier();
        if (LAYER == 1) {
            unsigned* zb = (unsigned*)outv;
            #pragma unroll
            for (int i = 0; i < 8; ++i) {
                int nn = 2 * i + (lane >> 5), cc = lane & 31;
                int node = node0 + nn;
                if (node < n) {
                    float2 rd = *(const float2*)&Cw[nn * 68 + 2 * cc];
                    zb[(size_t)node * 32 + cc] = bfpack(rd.x, rd.y);
                }
            }
        } else {
            float* out = (float*)outv;
            #pragma unroll
            for (int i = 0; i < 16; ++i) {
                int node = node0 + i;
                if (node < n) out[(size_t)node * 64 + lane] = Cw[i * 68 + lane];
            }
        }
        __builtin_amdgcn_wave_barrier();
    }
}

extern "C" void kernel_launch(void* const* d_in, const int* in_sizes, int n_in,
                              void* d_out, int out_size, void* d_ws, size_t ws_size,
                              hipStream_t stream)
{
    const float* x   = (const float*)d_in[0];
    const float* W1p = (const float*)d_in[1];
    const float* b1p = (const float*)d_in[2];
    const float* W1n = (const float*)d_in[3];
    const float* b1n = (const float*)d_in[4];
    const float* W2p = (const float*)d_in[5];
    const float* b2p = (const float*)d_in[6];
    const float* W2n = (const float*)d_in[7];
    const float* b2n = (const float*)d_in[8];
    const int*   pos = (const int*)d_in[9];
    const int*   neg = (const int*)d_in[10];

    int n = in_sizes[0] / 64;       // 100000
    int E = in_sizes[9] / 2;        // 1250000
    int n2 = 2 * n;

    // ws (4B units): deg[2n] cur[2n] bsum[1024] ticket[16] col[2E] xb[32n]
    //                zb[32n] A[64n]
    int*      deg    = (int*)d_ws;
    int*      cur    = deg + n2;
    int*      bsum   = cur + n2;
    int*      ticket = bsum + 1024;
    int*      col    = ticket + 16;
    unsigned* xb     = (unsigned*)(col + 2 * (size_t)E);
    unsigned* zb     = xb + (size_t)n * 32;
    unsigned* Abuf   = zb + (size_t)n * 32;

    // zero deg + (cur, bsum don't need it) + ticket: just zero the prefix
    (void)hipMemsetAsync(d_ws, 0, ((size_t)n2 * 2 + 1024 + 16) * sizeof(int), stream);

    int eblocks = (2 * E + 255) / 256;
    int sblocks = (n2 + 255) / 256;
    int cvtBlocks = (n * 32 + 255) / 256;

    pre_k  <<<cvtBlocks + eblocks, 256, 0, stream>>>((const fv2*)x, xb, n * 32,
                                                     pos, neg, deg, E, n, cvtBlocks);
    scan1_k<<<sblocks, 256, 0, stream>>>(deg, cur, bsum, n2);
    scan2_k<<<1, 1024, 0, stream>>>(bsum, sblocks);
    scan3_k<<<sblocks, 256, 0, stream>>>(cur, bsum, n2);
    fill_k <<<4096, 64, 0, stream>>>(pos, neg, cur, col, ticket, E, n);

    int gblocks = 2048;      // 8 blocks/CU, grid-stride over nodes
    int mblocks = 768;       // gemm: 3 blocks/CU resident

    gather_k<<<gblocks, 256, 0, stream>>>(xb, cur, col, Abuf, n);
    gemm_k<1><<<mblocks, 256, 0, stream>>>(Abuf, xb, W1p, b1p, W1n, b1n, zb, n);
    gather_k<<<gblocks, 256, 0, stream>>>(zb, cur, col, Abuf, n);
    gemm_k<2><<<mblocks, 256, 0, stream>>>(Abuf, zb, W2p, b2p, W2n, b2n, d_out, n);
}

// Round 9
// 527.711 us; speedup vs baseline: 1.2217x; 1.2217x over previous
//
#include <hip/hip_runtime.h>
#include <math.h>

// ---------------------------------------------------------------------------
// SGCN forward — R8: two-level bucket scatter for CSR fill.
//
// R6/R7 post-mortem: nt-loads and XCD-pinning both failed to kill fill's
// write amplification (109-121MB for a 10MB col[]) -> the active scatter
// line-set itself must shrink. R8 multi-split:
//   pass1: per-block LDS histogram over 196 buckets (1024 nodes) -> one
//          global atomic per (block,bucket) -> pairs written sequentially
//          per bucket (196 x 64B active lines, L2-resident).
//   pass2: bucket's pairs occupy exactly its col span; block re-scatters
//          inside a 51KB col window + 4KB cur window -> write amp ~1.
// pairs (20MB) overlays Abuf (live only after fill).
// ---------------------------------------------------------------------------

typedef __attribute__((ext_vector_type(8))) __bf16 bf16x8;
typedef __attribute__((ext_vector_type(4))) float f32x4;
typedef __attribute__((ext_vector_type(2))) unsigned uv2;
typedef __attribute__((ext_vector_type(4))) unsigned uv4;
typedef __attribute__((ext_vector_type(2))) float fv2;

#define NPB_SHIFT 10          // nodes per bucket = 1024
#define TILE 4096             // edges per pass1 block (16 per thread)

__device__ inline unsigned bfpack(float lo, float hi) {
    unsigned a = __float_as_uint(lo), b = __float_as_uint(hi);
    a += 0x7fffu + ((a >> 16) & 1u);          // RNE to bf16
    b += 0x7fffu + ((b >> 16) & 1u);
    return (a >> 16) | (b & 0xffff0000u);
}
__device__ inline float bflo(unsigned p) { return __uint_as_float(p << 16); }
__device__ inline float bfhi(unsigned p) { return __uint_as_float(p & 0xffff0000u); }

__device__ inline float tanh_fast(float x) {
    float e = __builtin_amdgcn_exp2f(x * 2.8853900817779268f);
    return 1.0f - 2.0f * __builtin_amdgcn_rcpf(e + 1.0f);
}

__device__ inline bf16x8 as_frag(uv4 u) { return __builtin_bit_cast(bf16x8, u); }

// ------------------------------- CSR build ---------------------------------

// blocks [0, cvtBlocks): fp32 -> bf16-pair convert of x.
// blocks [cvtBlocks, ...): degree histogram with nt edge-stream reads.
__global__ void __launch_bounds__(256) pre_k(
    const fv2* __restrict__ xf, unsigned* __restrict__ xb, int m,
    const int* __restrict__ pos, const int* __restrict__ neg,
    int* __restrict__ deg, int E, int n, int cvtBlocks)
{
    if ((int)blockIdx.x < cvtBlocks) {
        int i = blockIdx.x * 256 + threadIdx.x;
        if (i < m) {
            fv2 v = __builtin_nontemporal_load(&xf[i]);
            xb[i] = bfpack(v.x, v.y);
        }
    } else {
        int e = (blockIdx.x - cvtBlocks) * 256 + threadIdx.x;
        if (e < E)
            atomicAdd(&deg[__builtin_nontemporal_load(&pos[E + e])], 1);
        else if (e < 2 * E)
            atomicAdd(&deg[n + __builtin_nontemporal_load(&neg[E + (e - E)])], 1);
    }
}

__global__ void __launch_bounds__(256) scan1_k(
    const int* __restrict__ deg, int* __restrict__ cur,
    int* __restrict__ bsum, int n2)
{
    __shared__ int s[256];
    int tid = threadIdx.x;
    int i = blockIdx.x * 256 + tid;
    int v = (i < n2) ? deg[i] : 0;
    s[tid] = v;
    __syncthreads();
    for (int off = 1; off < 256; off <<= 1) {
        int t = (tid >= off) ? s[tid - off] : 0;
        __syncthreads();
        s[tid] += t;
        __syncthreads();
    }
    if (i < n2) cur[i] = s[tid] - v;
    if (tid == 255) bsum[blockIdx.x] = s[255];
}

__global__ void __launch_bounds__(1024) scan2_k(int* __restrict__ bsum, int nb)
{
    __shared__ int s[1024];
    int tid = threadIdx.x;
    int v = (tid < nb) ? bsum[tid] : 0;
    s[tid] = v;
    __syncthreads();
    for (int off = 1; off < 1024; off <<= 1) {
        int t = (tid >= off) ? s[tid - off] : 0;
        __syncthreads();
        s[tid] += t;
        __syncthreads();
    }
    if (tid < nb) bsum[tid] = s[tid] - v;
}

__global__ void __launch_bounds__(256) scan3_k(
    int* __restrict__ cur, const int* __restrict__ bsum, int n2)
{
    int i = blockIdx.x * 256 + threadIdx.x;
    if (i < n2) cur[i] += bsum[blockIdx.x];
}

// bucket bases from the (still pristine) exclusive row-start prefix in cur.
__global__ void __launch_bounds__(256) binit_k(
    const int* __restrict__ cur, int* __restrict__ bbase, int* __restrict__ bcur,
    int E2, int nbkt)
{
    int b = blockIdx.x * 256 + threadIdx.x;
    if (b < nbkt) {
        int v = cur[b << NPB_SHIFT];
        bbase[b] = v;
        bcur[b]  = v;
    }
    if (b == nbkt) bbase[nbkt] = E2;
}

// pass1: LDS-histogram multi-split into per-bucket sequential pair streams.
__global__ void __launch_bounds__(256) pass1_k(
    const int* __restrict__ pos, const int* __restrict__ neg,
    int* __restrict__ bcur, uv2* __restrict__ pairs, int E, int n, int nbkt)
{
    __shared__ int lcnt[256];
    int tid = threadIdx.x;
    int base = blockIdx.x * TILE;
    int total = 2 * E;
    lcnt[tid] = 0;
    __syncthreads();
    int node[16], src[16];
    #pragma unroll
    for (int j = 0; j < 16; ++j) {
        int e = base + j * 256 + tid;
        if (e < total) {
            if (e < E) {
                node[j] = __builtin_nontemporal_load(&pos[E + e]);
                src[j]  = __builtin_nontemporal_load(&pos[e]);
            } else {
                node[j] = n + __builtin_nontemporal_load(&neg[e]);      // neg[E+f]
                src[j]  = __builtin_nontemporal_load(&neg[e - E]);      // neg[f]
            }
            atomicAdd(&lcnt[node[j] >> NPB_SHIFT], 1);
        } else node[j] = -1;
    }
    __syncthreads();
    if (tid < nbkt) {
        int c = lcnt[tid];
        lcnt[tid] = c ? atomicAdd(&bcur[tid], c) : 0;   // now holds global cursor
    }
    __syncthreads();
    #pragma unroll
    for (int j = 0; j < 16; ++j) {
        if (node[j] >= 0) {
            int slot = atomicAdd(&lcnt[node[j] >> NPB_SHIFT], 1);
            uv2 p; p.x = (unsigned)node[j]; p.y = (unsigned)src[j];
            pairs[slot] = p;
        }
    }
}

// pass2: scatter within one bucket's 51KB col window (grid = 4*nbkt).
__global__ void __launch_bounds__(256) pass2_k(
    const uv2* __restrict__ pairs, const int* __restrict__ bbase,
    int* __restrict__ cur, int* __restrict__ col, int nbkt)
{
    int b = blockIdx.x >> 2, q = blockIdx.x & 3;
    int i0 = bbase[b], i1 = bbase[b + 1];
    int len = i1 - i0;
    int s = i0 + (int)(((long long)len * q) >> 2);
    int e = i0 + (int)(((long long)len * (q + 1)) >> 2);
    for (int i = s + (int)threadIdx.x; i < e; i += 256) {
        uv2 p = pairs[i];
        int slot = atomicAdd(&cur[(int)p.x], 1);
        col[slot] = (int)p.y;
    }
}

// ----------------------------- pull gather ---------------------------------
// One wave per node (grid-stride). lane = 8g+f: 8 lanes cover a 128B bf16
// row (16B uv4/lane). Groups 0..3 pull pos edges, 4..7 pull neg.
__global__ void __launch_bounds__(256, 8) gather_k(
    const unsigned* __restrict__ tab,   // n x 32 uints (bf16 pairs)
    const int* __restrict__ cur, const int* __restrict__ col,
    unsigned* __restrict__ Aout,        // n x 64 uints
    int n)
{
    int tid = threadIdx.x;
    int wave = tid >> 6, lane = tid & 63, g = lane >> 3, f = lane & 7;
    int gq = g & 3;
    bool isNeg = g >= 4;
    int stride = gridDim.x * 4;
    for (int node = blockIdx.x * 4 + wave; node < n; node += stride) {
        int p0 = node ? cur[node - 1] : 0;
        int p1 = cur[node];
        int q0 = cur[n + node - 1];     // node==0 -> cur[n-1] == E
        int q1 = cur[n + node];
        int it0 = isNeg ? q0 : p0;
        int it1 = isNeg ? q1 : p1;
        float a0 = 0.f, a1 = 0.f, a2 = 0.f, a3 = 0.f;
        float a4 = 0.f, a5 = 0.f, a6 = 0.f, a7 = 0.f;
        #pragma unroll 2
        for (int it = it0 + gq; it < it1; it += 4) {
            int s = __builtin_nontemporal_load(&col[it]);
            uv4 t = *(const uv4*)(tab + (size_t)s * 32 + 4 * f);
            a0 += bflo(t.x); a1 += bfhi(t.x);
            a2 += bflo(t.y); a3 += bfhi(t.y);
            a4 += bflo(t.z); a5 += bfhi(t.z);
            a6 += bflo(t.w); a7 += bfhi(t.w);
        }
        a0 += __shfl_xor(a0, 8);  a1 += __shfl_xor(a1, 8);
        a2 += __shfl_xor(a2, 8);  a3 += __shfl_xor(a3, 8);
        a4 += __shfl_xor(a4, 8);  a5 += __shfl_xor(a5, 8);
        a6 += __shfl_xor(a6, 8);  a7 += __shfl_xor(a7, 8);
        a0 += __shfl_xor(a0, 16); a1 += __shfl_xor(a1, 16);
        a2 += __shfl_xor(a2, 16); a3 += __shfl_xor(a3, 16);
        a4 += __shfl_xor(a4, 16); a5 += __shfl_xor(a5, 16);
        a6 += __shfl_xor(a6, 16); a7 += __shfl_xor(a7, 16);
        float r = 1.0f / (float)max(it1 - it0, 1);
        if (g == 0 || g == 4) {
            uv4 o;
            o.x = bfpack(a0 * r, a1 * r);
            o.y = bfpack(a2 * r, a3 * r);
            o.z = bfpack(a4 * r, a5 * r);
            o.w = bfpack(a6 * r, a7 * r);
            unsigned* dst = Aout + (size_t)node * 64 + (isNeg ? 32 : 0) + 4 * f;
            __builtin_nontemporal_store(o, (uv4*)dst);
        }
    }
}

// ------------------------------ MFMA dense ---------------------------------
template<int LAYER>
__global__ void __launch_bounds__(256, 3) gemm_k(
    const unsigned* __restrict__ A,      // n x 64 uints  [agg_p|agg_n]
    const unsigned* __restrict__ T,      // n x 32 uints  (x or z bf16)
    const float* __restrict__ Wp, const float* __restrict__ bp,
    const float* __restrict__ Wn, const float* __restrict__ bn,
    void* __restrict__ outv, int n)
{
    __shared__ unsigned short Bl[64 * 200];   // 25.6 KB
    __shared__ float Cs[4][16 * 68];          // 17.4 KB, per-wave C transpose
    int tid = threadIdx.x;
    for (int idx = tid; idx < 64 * 192; idx += 256) {
        int k = idx >> 6, nn = idx & 63;
        float v = 0.f;
        if (LAYER == 1) {
            if (nn < 32) { if (k < 64) v = Wp[k * 32 + nn];
                           else if (k >= 128) v = Wp[(k - 64) * 32 + nn]; }
            else         { if (k >= 64) v = Wn[(k - 64) * 32 + (nn - 32)]; }
        } else {
            if (nn < 32) { if (k < 32) v = Wp[k * 32 + nn];
                           else if (k >= 96 && k < 160) v = Wp[(k - 64) * 32 + nn]; }
            else         { if (k >= 32 && k < 96) v = Wn[(k - 32) * 32 + (nn - 32)];
                           else if (k >= 160) v = Wn[(k - 96) * 32 + (nn - 32)]; }
        }
        unsigned u = __float_as_uint(v);
        u += 0x7fffu + ((u >> 16) & 1u);
        Bl[nn * 200 + k] = (unsigned short)(u >> 16);
    }
    __syncthreads();

    int wave = tid >> 6, lane = tid & 63;
    int lm = lane & 15, lg = lane >> 4;

    bf16x8 Bf[4][6];
    #pragma unroll
    for (int t = 0; t < 4; ++t)
        #pragma unroll
        for (int s = 0; s < 6; ++s)
            Bf[t][s] = *(const bf16x8*)&Bl[(t * 16 + lm) * 200 + s * 32 + lg * 8];

    float bias[4];
    #pragma unroll
    for (int t = 0; t < 4; ++t) {
        int nc = t * 16 + lm;
        bias[t] = (nc < 32) ? bp[nc] : bn[nc - 32];
    }

    float* Cw = Cs[wave];
    int ntiles = (n + 15) >> 4;
    for (int tile = blockIdx.x * 4 + wave; tile < ntiles; tile += gridDim.x * 4) {
        int node0 = tile * 16;
        int ra = min(node0 + lm, n - 1);          // A-frag: m = lane&15
        const uv4* Arow = (const uv4*)(A + (size_t)ra * 64);
        const uv4* Trow = (const uv4*)(T + (size_t)ra * 32);
        bf16x8 Af[6];
        #pragma unroll
        for (int s = 0; s < 4; ++s)
            Af[s] = as_frag(__builtin_nontemporal_load(&Arow[s * 4 + lg]));
        #pragma unroll
        for (int s = 0; s < 2; ++s) Af[4 + s] = as_frag(Trow[s * 4 + lg]);

        #pragma unroll
        for (int t = 0; t < 4; ++t) {
            f32x4 c = {0.f, 0.f, 0.f, 0.f};
            #pragma unroll
            for (int s = 0; s < 6; ++s)
                c = __builtin_amdgcn_mfma_f32_16x16x32_bf16(Af[s], Bf[t][s], c, 0, 0, 0);
            #pragma unroll
            for (int r = 0; r < 4; ++r)
                Cw[(lg * 4 + r) * 68 + t * 16 + lm] = tanh_fast(c[r] + bias[t]);
        }
        __builtin_amdgcn_wave_barrier();
        if (LAYER == 1) {
            unsigned* zb = (unsigned*)outv;
            #pragma unroll
            for (int i = 0; i < 8; ++i) {
                int nn = 2 * i + (lane >> 5), cc = lane & 31;
                int node = node0 + nn;
                if (node < n) {
                    float2 rd = *(const float2*)&Cw[nn * 68 + 2 * cc];
                    zb[(size_t)node * 32 + cc] = bfpack(rd.x, rd.y);
                }
            }
        } else {
            float* out = (float*)outv;
            #pragma unroll
            for (int i = 0; i < 16; ++i) {
                int node = node0 + i;
                if (node < n) out[(size_t)node * 64 + lane] = Cw[i * 68 + lane];
            }
        }
        __builtin_amdgcn_wave_barrier();
    }
}

extern "C" void kernel_launch(void* const* d_in, const int* in_sizes, int n_in,
                              void* d_out, int out_size, void* d_ws, size_t ws_size,
                              hipStream_t stream)
{
    const float* x   = (const float*)d_in[0];
    const float* W1p = (const float*)d_in[1];
    const float* b1p = (const float*)d_in[2];
    const float* W1n = (const float*)d_in[3];
    const float* b1n = (const float*)d_in[4];
    const float* W2p = (const float*)d_in[5];
    const float* b2p = (const float*)d_in[6];
    const float* W2n = (const float*)d_in[7];
    const float* b2n = (const float*)d_in[8];
    const int*   pos = (const int*)d_in[9];
    const int*   neg = (const int*)d_in[10];

    int n = in_sizes[0] / 64;       // 100000
    int E = in_sizes[9] / 2;        // 1250000
    int n2 = 2 * n;
    int nbkt = (n2 + ((1 << NPB_SHIFT) - 1)) >> NPB_SHIFT;   // 196

    // ws (4B units): deg[2n] cur[2n] bsum[1024] bbase[512] bcur[512] col[2E]
    //                xb[32n] zb[32n] Abuf[64n]  (pairs overlays Abuf)
    int*      deg   = (int*)d_ws;
    int*      cur   = deg + n2;
    int*      bsum  = cur + n2;
    int*      bbase = bsum + 1024;
    int*      bcur  = bbase + 512;
    int*      col   = bcur + 512;
    unsigned* xb    = (unsigned*)(col + 2 * (size_t)E);
    unsigned* zb    = xb + (size_t)n * 32;
    unsigned* Abuf  = zb + (size_t)n * 32;
    uv2*      pairs = (uv2*)Abuf;

    (void)hipMemsetAsync(deg, 0, (size_t)n2 * sizeof(int), stream);

    int eblocks = (2 * E + 255) / 256;
    int sblocks = (n2 + 255) / 256;
    int cvtBlocks = (n * 32 + 255) / 256;

    pre_k  <<<cvtBlocks + eblocks, 256, 0, stream>>>((const fv2*)x, xb, n * 32,
                                                     pos, neg, deg, E, n, cvtBlocks);
    scan1_k<<<sblocks, 256, 0, stream>>>(deg, cur, bsum, n2);
    scan2_k<<<1, 1024, 0, stream>>>(bsum, sblocks);
    scan3_k<<<sblocks, 256, 0, stream>>>(cur, bsum, n2);
    binit_k<<<(nbkt + 256) / 256, 256, 0, stream>>>(cur, bbase, bcur, 2 * E, nbkt);
    pass1_k<<<(2 * E + TILE - 1) / TILE, 256, 0, stream>>>(pos, neg, bcur, pairs, E, n, nbkt);
    pass2_k<<<4 * nbkt, 256, 0, stream>>>(pairs, bbase, cur, col, nbkt);

    int gblocks = 2048;      // 8 blocks/CU, grid-stride over nodes
    int mblocks = 768;       // gemm: 3 blocks/CU resident

    gather_k<<<gblocks, 256, 0, stream>>>(xb, cur, col, Abuf, n);
    gemm_k<1><<<mblocks, 256, 0, stream>>>(Abuf, xb, W1p, b1p, W1n, b1n, zb, n);
    gather_k<<<gblocks, 256, 0, stream>>>(zb, cur, col, Abuf, n);
    gemm_k<2><<<mblocks, 256, 0, stream>>>(Abuf, zb, W2p, b2p, W2n, b2n, d_out, n);
}